// Round 1
// baseline (1763.047 us; speedup 1.0000x reference)
//
#include <hip/hip_runtime.h>
#include <hip/hip_bf16.h>

#define NTOK 49
#define DIM  256
#define NH   8
#define DH   32
#define NB   2048

// ---------- dtype-polymorphic load/store ----------
__device__ __forceinline__ float ldf(const float* p, size_t i) { return p[i]; }
__device__ __forceinline__ float ldf(const __hip_bfloat16* p, size_t i) { return __bfloat162float(p[i]); }
__device__ __forceinline__ void stf(float* p, size_t i, float v) { p[i] = v; }
__device__ __forceinline__ void stf(__hip_bfloat16* p, size_t i, float v) { p[i] = __float2bfloat16(v); }

// ---------- dtype detector ----------
// Genuine fp32 N(0,1) data: low 16 bits of each word are uniform mantissa bits
// -> "bf16 exponent" of low half is ~uniform over [0,255] (~12% in window).
// bf16-converted data: low half IS a bf16 N(0,1) sample -> exponent in [110,140]
// essentially always. Count hits over 64 words; >=32 => bf16.
__global__ void dtype_detect_kernel(const unsigned int* __restrict__ x, int* flag) {
  if (blockIdx.x == 0 && threadIdx.x == 0) {
    int hits = 0;
    for (int i = 0; i < 64; ++i) {
      unsigned int lo = x[i] & 0xFFFFu;
      unsigned int e = (lo >> 7) & 0xFFu;
      if (e >= 110u && e <= 140u) hits++;
    }
    *flag = (hits >= 32) ? 1 : 0;   // 1 = bf16, 0 = fp32
  }
}

// ---------- fused QKV-projection + window attention (one block per (window b, head h)) ----------
template <typename T>
__global__ __launch_bounds__(256, 2)
void win_attn_kernel(const T* __restrict__ x, const T* __restrict__ maskp,
                     const T* __restrict__ qkv_w, const T* __restrict__ qkv_b,
                     const T* __restrict__ rpb_table, const int* __restrict__ rel_index,
                     T* __restrict__ out, const int* __restrict__ flag, int want)
{
  if (*flag != want) return;

  const int b = blockIdx.x;
  const int h = blockIdx.y;
  const int tid = threadIdx.x;
  const int tx = tid & 15;      // 0..15
  const int ty = tid >> 4;      // 0..15

  // LDS: 64*68 + 96*68 + 3*49*36 + 49*52 floats = 74,880 B -> 2 blocks/CU
  __shared__ __align__(16) float xst[64][68];    // x k-tile, rows 49..63 unused/garbage
  __shared__ __align__(16) float wt[96][68];     // qkv_w head-slice k-tile (96 rows = 3*32)
  __shared__ __align__(16) float qs[NTOK][36];   // q (pre-scaled)
  __shared__ __align__(16) float ks2[NTOK][36];  // k
  __shared__ __align__(16) float vs[NTOK][36];   // v
  __shared__ __align__(16) float sm[NTOK][52];   // scores / probs

  const float SCALE = 0.17677669529663687f;      // 32^-0.5

  // ---- per-head QKV GEMM: (49x256) @ (256x96)^T, K-tiled by 64 ----
  float acc[4][6];
#pragma unroll
  for (int i = 0; i < 4; ++i)
#pragma unroll
    for (int m = 0; m < 6; ++m) acc[i][m] = 0.0f;

  const size_t xbase = (size_t)b * NTOK * DIM;

  for (int kt = 0; kt < DIM; kt += 64) {
    // stage x tile: 49 x 64
    for (int i = tid; i < NTOK * 64; i += 256) {
      int n = i >> 6, kk = i & 63;
      xst[n][kk] = ldf(x, xbase + (size_t)n * DIM + kt + kk);
    }
    // stage qkv_w head-slice tile: rows j=0..95 -> global row c*256 + h*32 + d
    for (int i = tid; i < 96 * 64; i += 256) {
      int j = i >> 6, kk = i & 63;
      int c = j >> 5, d = j & 31;
      wt[j][kk] = ldf(qkv_w, (size_t)(c * DIM + h * DH + d) * DIM + kt + kk);
    }
    __syncthreads();

#pragma unroll 2
    for (int kk = 0; kk < 64; kk += 4) {
      float4 av[4], bv[6];
#pragma unroll
      for (int i = 0; i < 4; ++i) av[i] = *(const float4*)&xst[ty + 16 * i][kk];
#pragma unroll
      for (int m = 0; m < 6; ++m) bv[m] = *(const float4*)&wt[tx + 16 * m][kk];
#pragma unroll
      for (int i = 0; i < 4; ++i)
#pragma unroll
        for (int m = 0; m < 6; ++m) {
          acc[i][m] += av[i].x * bv[m].x;
          acc[i][m] += av[i].y * bv[m].y;
          acc[i][m] += av[i].z * bv[m].z;
          acc[i][m] += av[i].w * bv[m].w;
        }
    }
    __syncthreads();
  }

  // epilogue: bias, scale q, scatter into q/k/v LDS
#pragma unroll
  for (int i = 0; i < 4; ++i) {
    int n = ty + 16 * i;
    if (n < NTOK) {
#pragma unroll
      for (int m = 0; m < 6; ++m) {
        int j = tx + 16 * m;
        int c = j >> 5, d = j & 31;
        float v = acc[i][m] + ldf(qkv_b, c * DIM + h * DH + d);
        if (c == 0)      qs[n][d] = v * SCALE;
        else if (c == 1) ks2[n][d] = v;
        else             vs[n][d] = v;
      }
    }
  }
  __syncthreads();

  // ---- scores: S[i][j] = q_i . k_j + rpb + mask ----
  const int w = b & 63;  // window index within image (mask leading dim)
  for (int e = tid; e < NTOK * NTOK; e += 256) {
    int i = e / 49, j = e % 49;
    const float4* qi = (const float4*)qs[i];
    const float4* kj = (const float4*)ks2[j];
    float s = 0.0f;
#pragma unroll
    for (int d4 = 0; d4 < 8; ++d4) {
      float4 a = qi[d4], c = kj[d4];
      s += a.x * c.x + a.y * c.y + a.z * c.z + a.w * c.w;
    }
    s += ldf(rpb_table, (size_t)rel_index[e] * NH + h);
    s += ldf(maskp, (size_t)w * NTOK * NTOK + e);
    sm[i][j] = s;
  }
  __syncthreads();

  // ---- softmax per row (threads 0..48) ----
  if (tid < NTOK) {
    int i = tid;
    float mx = -3.4e38f;
    for (int j = 0; j < NTOK; ++j) mx = fmaxf(mx, sm[i][j]);
    float sum = 0.0f;
    for (int j = 0; j < NTOK; ++j) {
      float ev = __expf(sm[i][j] - mx);
      sm[i][j] = ev;
      sum += ev;
    }
    float inv = 1.0f / sum;
    for (int j = 0; j < NTOK; ++j) sm[i][j] *= inv;
  }
  __syncthreads();

  // ---- O = P @ V, write to out[b, i, h*32+d] ----
  for (int e = tid; e < NTOK * DH; e += 256) {
    int i = e >> 5, d = e & 31;
    float o = 0.0f;
    for (int j = 0; j < NTOK; ++j) o += sm[i][j] * vs[j][d];
    stf(out, ((size_t)b * NTOK + i) * DIM + h * DH + d, o);
  }
}

// ---------- in-place output projection: out = out @ proj_w^T + proj_b ----------
// Each block owns 32 rows; stages them to LDS before writing back -> no hazard.
template <typename T>
__global__ __launch_bounds__(256, 2)
void proj_kernel(T* __restrict__ out, const T* __restrict__ proj_w,
                 const T* __restrict__ proj_b, const int* __restrict__ flag, int want)
{
  if (*flag != want) return;

  const int tid = threadIdx.x;
  const int tx = tid & 15;
  const int ty = tid >> 4;
  const size_t r0 = (size_t)blockIdx.x * 32;   // 100352 rows / 32 = 3136 blocks exact

  __shared__ __align__(16) float xs[32][260];   // 33.3 KB
  __shared__ __align__(16) float pwt[256][36];  // 36.9 KB (k-tile 32)

  // stage 32 rows of attn-out
  for (int i = tid; i < 32 * 256; i += 256) {
    int n = i >> 8, c = i & 255;
    xs[n][c] = ldf((const T*)out, (r0 + n) * DIM + c);
  }
  __syncthreads();

  float acc[2][16];
#pragma unroll
  for (int i = 0; i < 2; ++i)
#pragma unroll
    for (int m = 0; m < 16; ++m) acc[i][m] = 0.0f;

  for (int kt = 0; kt < DIM; kt += 32) {
    // stage proj_w tile: all 256 output cols x 32 k
    for (int i = tid; i < 256 * 32; i += 256) {
      int j = i >> 5, kk = i & 31;
      pwt[j][kk] = ldf(proj_w, (size_t)j * DIM + kt + kk);
    }
    __syncthreads();

#pragma unroll 2
    for (int kk = 0; kk < 32; kk += 4) {
      float4 av[2], bv[16];
#pragma unroll
      for (int i = 0; i < 2; ++i) av[i] = *(const float4*)&xs[ty + 16 * i][kt + kk];
#pragma unroll
      for (int m = 0; m < 16; ++m) bv[m] = *(const float4*)&pwt[tx + 16 * m][kk];
#pragma unroll
      for (int i = 0; i < 2; ++i)
#pragma unroll
        for (int m = 0; m < 16; ++m) {
          acc[i][m] += av[i].x * bv[m].x;
          acc[i][m] += av[i].y * bv[m].y;
          acc[i][m] += av[i].z * bv[m].z;
          acc[i][m] += av[i].w * bv[m].w;
        }
    }
    __syncthreads();
  }

#pragma unroll
  for (int i = 0; i < 2; ++i) {
    int n = ty + 16 * i;
#pragma unroll
    for (int m = 0; m < 16; ++m) {
      int c = tx + 16 * m;
      stf(out, (r0 + n) * DIM + c, acc[i][m] + ldf(proj_b, c));
    }
  }
}

extern "C" void kernel_launch(void* const* d_in, const int* in_sizes, int n_in,
                              void* d_out, int out_size, void* d_ws, size_t ws_size,
                              hipStream_t stream) {
  const void* x      = d_in[0];
  const void* maskp  = d_in[1];
  const void* qkv_w  = d_in[2];
  const void* qkv_b  = d_in[3];
  const void* proj_w = d_in[4];
  const void* proj_b = d_in[5];
  const void* rpb    = d_in[6];
  const int*  rel    = (const int*)d_in[7];

  int* flag = (int*)d_ws;

  dtype_detect_kernel<<<dim3(1), dim3(64), 0, stream>>>((const unsigned int*)x, flag);

  dim3 gA(NB, NH);
  win_attn_kernel<float><<<gA, 256, 0, stream>>>(
      (const float*)x, (const float*)maskp, (const float*)qkv_w, (const float*)qkv_b,
      (const float*)rpb, rel, (float*)d_out, flag, 0);
  win_attn_kernel<__hip_bfloat16><<<gA, 256, 0, stream>>>(
      (const __hip_bfloat16*)x, (const __hip_bfloat16*)maskp, (const __hip_bfloat16*)qkv_w,
      (const __hip_bfloat16*)qkv_b, (const __hip_bfloat16*)rpb, rel,
      (__hip_bfloat16*)d_out, flag, 1);

  dim3 gB(3136);
  proj_kernel<float><<<gB, 256, 0, stream>>>(
      (float*)d_out, (const float*)proj_w, (const float*)proj_b, flag, 0);
  proj_kernel<__hip_bfloat16><<<gB, 256, 0, stream>>>(
      (__hip_bfloat16*)d_out, (const __hip_bfloat16*)proj_w, (const __hip_bfloat16*)proj_b,
      flag, 1);
}